// Round 16
// baseline (81.478 us; speedup 1.0000x reference)
//
#include <hip/hip_runtime.h>

// LBP for semantic dependency parsing — label-difference form, all 3
// iterations fused, u-SPACE chain (u = 2^D), fp16 F payload, direct
// register double-buffered loads.
//
// r15 post-mortem: (1024,8)+waves_per_eu(8,8) gave 80% occupancy but the
// allocator STILL overshot to VGPR=32 and spilled (WRITE 20.5 MB scratch).
// r12 evidence: declaring (1024,4) lands VGPR=60 with zero spill. Since
// launch_bounds is a compiler floor, not a runtime cap, a <=64-VGPR
// allocation lets the HW co-schedule 2 blocks/CU anyway (8 waves/SIMD x
// 60 VGPR = 480 <= 512; LDS 11 KB). So (1024,4) + tiny pressure trims
// should deliver r15's occupancy AND r12's spill-free allocation.
//
//   F[b,i,j,k] = 2^(log2e*s) = e^s                (only use of the scores)
//   u_1 = (p1 + F)*r1,          p1 = 2^(-q0[i]), r1 = 1/(1+p1)
//   u_t = (p + F)/(1 + p),      p = u_{t-1} * 2^(-q_{t-1}[i])
//   q_t[k] = q0[k] + mask[k] * sum_i log2(u_s*u_c*u_g)[i,k]
//                               * mask[i]*(i!=j)*(i!=k)
//   out[b,k,j] = 1/(1+2^(-q_3[k]))
//
// Geometry: block (b,j), 1024 thr, 16 waves. Thread = (lane -> k in
// {2*lane, 2*lane+1}, wave wv -> row 16r+wv of tile r, r=0..7).
// Wave-uniform row => coherent branch; row constants hoisted to SGPRs via
// readfirstlane; direct red[wv][k] reduction (no shfl). fp16 F payload =
// 24 VGPR (precision proven r7-r15: absmax 0.0078 vs threshold 0.02).
// Pass 3 recomputes the chain from F (2 rcp/score).

#define TS 128
#define SS (TS * TS)

typedef float    f2v __attribute__((ext_vector_type(2)));
typedef _Float16 h2v __attribute__((ext_vector_type(2)));

constexpr float LOG2E = 1.4426950408889634f;

__device__ __forceinline__ float rcpf(float x)   { return __builtin_amdgcn_rcpf(x); }
__device__ __forceinline__ float clampe(float e) { return fminf(fmaxf(e, -126.0f), 60.0f); }
__device__ __forceinline__ float rfl(float x) {   // wave-uniform value -> SGPR
    return __int_as_float(__builtin_amdgcn_readfirstlane(__float_as_int(x)));
}

// ---- single-block mask format probe: f[0]!=0 byte mask, f[1]!=0 f32, else i32
__global__ void mask_probe(const unsigned char* __restrict__ m, int n, int* __restrict__ f) {
    __shared__ int s1, s23;
    if (threadIdx.x == 0) { s1 = 0; s23 = 0; }
    __syncthreads();
    unsigned a1 = 0, a23 = 0;
    const int n16 = n >> 4;
    const uint4* m4 = (const uint4*)m;
    for (int i = threadIdx.x; i < n16; i += 1024) {
        const uint4 v = m4[i];
        const unsigned o = v.x | v.y | v.z | v.w;
        a1  |= o & 0x0000FF00u;
        a23 |= o & 0xFFFF0000u;
    }
    for (int i = (n16 << 4) + threadIdx.x; i < n; i += 1024) {  // tail bytes
        const unsigned char b = m[i];
        const int r = i & 3;
        if (r == 1) a1 |= b;
        if (r >= 2) a23 |= b;
    }
    if (__any(a1 != 0)  && (threadIdx.x & 63) == 0) atomicOr(&s1, 1);
    if (__any(a23 != 0) && (threadIdx.x & 63) == 0) atomicOr(&s23, 1);
    __syncthreads();
    if (threadIdx.x == 0) { f[0] = s1; f[1] = s23; }
}

__global__ __launch_bounds__(1024, 4)
void lbp_fused(const float* __restrict__ s_edge,
               const float* __restrict__ sib,
               const float* __restrict__ cop,
               const float* __restrict__ grd,
               const void* __restrict__ mask,
               const int* __restrict__ flags,
               float* __restrict__ outp)
{
    __shared__ float red[16][TS];        // 8 KB: [wave][k]
    __shared__ float q0s[TS], p1s[TS], r1s[TS], g1s[TS], g2s[TS];
    __shared__ unsigned char mrow[TS];

    const int bj = blockIdx.x;
    const int b  = bj >> 7;
    const int j  = bj & (TS - 1);
    const int t  = threadIdx.x;
    const int lane = t & 63;            // k = 2*lane, 2*lane+1
    const int wv = t >> 6;              // wave 0..15; tile r -> row 16r+wv
    const int ka = 2 * lane, kb = 2 * lane + 1;

    // ---- per-column prologue ----
    if (t < TS) {
        const int i = t;
        const int idx = (b * TS + i) * TS + j;
        const float q0 = LOG2E * s_edge[idx];
        q0s[i] = q0;
        const int f1 = flags[0], f23 = flags[1];
        unsigned char mv;
        if (f1)       mv = ((const unsigned char*)mask)[idx] != 0;
        else if (f23) mv = ((const float*)mask)[idx] != 0.0f;
        else          mv = ((const int*)mask)[idx]   != 0;
        mrow[i] = mv;
        const float p1 = exp2f(clampe(-q0));
        p1s[i] = p1;
        r1s[i] = rcpf(1.0f + p1);
    }
    __syncthreads();

    // per-lane element base of (b, row0=wv, j, 2*lane)
    const size_t gbase = (size_t)b * (TS * SS) + (size_t)j * TS + (size_t)wv * SS + ka;

    // ---- pass 1 with register double-buffered direct loads ----
    h2v Fs[8], Fc[8], Fg[8];
    float a0 = 0.0f, a1 = 0.0f;
    f2v vs = *(const f2v*)(sib + gbase);
    f2v vc = *(const f2v*)(cop + gbase);
    f2v vg = *(const f2v*)(grd + gbase);
    #pragma unroll
    for (int r = 0; r < 8; ++r) {
        f2v nvs, nvc, nvg;
        if (r < 7) {
            const size_t g = gbase + (size_t)(16 * (r + 1)) * SS;
            nvs = *(const f2v*)(sib + g);
            nvc = *(const f2v*)(cop + g);
            nvg = *(const f2v*)(grd + g);
        }
        const int i = 16 * r + wv;                 // wave-uniform row
        f2v fs, fc, fg;
        fs[0] = exp2f(LOG2E * vs[0]);  fs[1] = exp2f(LOG2E * vs[1]);
        fc[0] = exp2f(LOG2E * vc[0]);  fc[1] = exp2f(LOG2E * vc[1]);
        fg[0] = exp2f(LOG2E * vg[0]);  fg[1] = exp2f(LOG2E * vg[1]);
        Fs[r] = __builtin_convertvector(fs, h2v);
        Fc[r] = __builtin_convertvector(fc, h2v);
        Fg[r] = __builtin_convertvector(fg, h2v);
        if ((mrow[i] != 0) && (i != j)) {          // wave-coherent branch
            const float p1 = rfl(p1s[i]), r1 = rfl(r1s[i]);
            const float l0 = __log2f(((p1 + fs[0]) * r1) * ((p1 + fc[0]) * r1)
                                     * ((p1 + fg[0]) * r1));
            const float l1 = __log2f(((p1 + fs[1]) * r1) * ((p1 + fc[1]) * r1)
                                     * ((p1 + fg[1]) * r1));
            if (i != ka) a0 += l0;
            if (i != kb) a1 += l1;
        }
        vs = nvs; vc = nvc; vg = nvg;
    }

    // reduce -> q1 -> g1  (each (wv,k) partial unique: direct store)
    { f2v v; v[0] = a0; v[1] = a1; *(f2v*)&red[wv][ka] = v; }
    __syncthreads();
    if (t < TS) {
        float tot = 0.0f;
        #pragma unroll
        for (int w = 0; w < 16; ++w) tot += red[w][t];
        const float q1 = q0s[t] + (mrow[t] ? tot : 0.0f);
        g1s[t] = exp2f(clampe(-q1));
    }
    __syncthreads();

    // ---- pass 2: u2 via 1 rcp/score, pure register math ----
    a0 = 0.0f; a1 = 0.0f;
    #pragma unroll
    for (int r = 0; r < 8; ++r) {
        const int i = 16 * r + wv;
        if ((mrow[i] != 0) && (i != j)) {
            const float p1 = rfl(p1s[i]), r1 = rfl(r1s[i]), g1 = rfl(g1s[i]);
            const f2v fs = __builtin_convertvector(Fs[r], f2v);
            const f2v fc = __builtin_convertvector(Fc[r], f2v);
            const f2v fg = __builtin_convertvector(Fg[r], f2v);
            float l[2];
            #pragma unroll
            for (int c = 0; c < 2; ++c) {
                float p, us, uc, ug;
                us = (p1 + fs[c]) * r1;  p = us * g1;  us = (p + fs[c]) * rcpf(1.0f + p);
                uc = (p1 + fc[c]) * r1;  p = uc * g1;  uc = (p + fc[c]) * rcpf(1.0f + p);
                ug = (p1 + fg[c]) * r1;  p = ug * g1;  ug = (p + fg[c]) * rcpf(1.0f + p);
                l[c] = __log2f(us * uc * ug);
            }
            if (i != ka) a0 += l[0];
            if (i != kb) a1 += l[1];
        }
    }

    // reduce -> q2 -> g2
    { f2v v; v[0] = a0; v[1] = a1; *(f2v*)&red[wv][ka] = v; }
    __syncthreads();
    if (t < TS) {
        float tot = 0.0f;
        #pragma unroll
        for (int w = 0; w < 16; ++w) tot += red[w][t];
        const float q2 = q0s[t] + (mrow[t] ? tot : 0.0f);
        g2s[t] = exp2f(clampe(-q2));
    }
    __syncthreads();

    // ---- pass 3: full chain recompute from F (2 rcp/score) ----
    a0 = 0.0f; a1 = 0.0f;
    #pragma unroll
    for (int r = 0; r < 8; ++r) {
        const int i = 16 * r + wv;
        if ((mrow[i] != 0) && (i != j)) {
            const float p1 = rfl(p1s[i]), r1 = rfl(r1s[i]);
            const float g1 = rfl(g1s[i]), g2 = rfl(g2s[i]);
            const f2v fs = __builtin_convertvector(Fs[r], f2v);
            const f2v fc = __builtin_convertvector(Fc[r], f2v);
            const f2v fg = __builtin_convertvector(Fg[r], f2v);
            float l[2];
            #pragma unroll
            for (int c = 0; c < 2; ++c) {
                float p, us, uc, ug;
                us = (p1 + fs[c]) * r1;  p = us * g1;  us = (p + fs[c]) * rcpf(1.0f + p);
                p = us * g2;  us = (p + fs[c]) * rcpf(1.0f + p);
                uc = (p1 + fc[c]) * r1;  p = uc * g1;  uc = (p + fc[c]) * rcpf(1.0f + p);
                p = uc * g2;  uc = (p + fc[c]) * rcpf(1.0f + p);
                ug = (p1 + fg[c]) * r1;  p = ug * g1;  ug = (p + fg[c]) * rcpf(1.0f + p);
                p = ug * g2;  ug = (p + fg[c]) * rcpf(1.0f + p);
                l[c] = __log2f(us * uc * ug);
            }
            if (i != ka) a0 += l[0];
            if (i != kb) a1 += l[1];
        }
    }

    // reduce -> q3 -> output
    { f2v v; v[0] = a0; v[1] = a1; *(f2v*)&red[wv][ka] = v; }
    __syncthreads();
    if (t < TS) {
        float tot = 0.0f;
        #pragma unroll
        for (int w = 0; w < 16; ++w) tot += red[w][t];
        const float q3 = q0s[t] + (mrow[t] ? tot : 0.0f);
        outp[(b * TS + t) * TS + j] = 1.0f / (1.0f + exp2f(clampe(-q3)));
    }
}

extern "C" void kernel_launch(void* const* d_in, const int* in_sizes, int n_in,
                              void* d_out, int out_size, void* d_ws, size_t ws_size,
                              hipStream_t stream) {
    const float* s_edge = (const float*)d_in[0];
    const float* sib    = (const float*)d_in[1];
    const float* cop    = (const float*)d_in[2];
    const float* grd    = (const float*)d_in[3];
    const void*  mask   = d_in[4];
    float* out = (float*)d_out;

    const int Bn = in_sizes[0] / (TS * TS);   // batch
    const int nMask = in_sizes[4];            // B*S*S elements

    int* flags = (int*)d_ws;

    mask_probe<<<1, 1024, 0, stream>>>((const unsigned char*)mask, nMask, flags);
    lbp_fused<<<Bn * TS, 1024, 0, stream>>>(s_edge, sib, cop, grd, mask, flags, out);
}

// Round 17
// 70.936 us; speedup vs baseline: 1.1486x; 1.1486x over previous
//
#include <hip/hip_runtime.h>

// LBP for semantic dependency parsing — label-difference form, all 3
// iterations fused, u-SPACE chain (u = 2^D), HYBRID F storage:
// tiles 0-2 in registers (9 VGPR), tiles 3-7 in LDS fp16 (60 KB).
//
// r15/r16 post-mortem pair measured the tradeoff exactly:
//   - 2 blocks/CU (80% occ) is worth ~10 us, but any >=8-wave declaration
//     makes the allocator squeeze to the 32-VGPR tier and spill (~20 MB).
//   - no-spill is worth ~10 us, but loose declarations lose the 2nd block.
// Fix: shrink TRUE demand to ~33 regs so the 32-tier is (nearly) honest:
// F payload 24 -> 9 regs by parking 5 of 8 tiles in LDS. LDS/block =
// 60K (F) + 8K (red) + 2.7K = ~71 KB -> 2 blocks = 142 <= 160 KB.
// LDS-F layout [tile][wave][k] fp16: lane stride 4 B -> 2 lanes/bank (free).
// Each thread reads only slots it wrote -> no extra barriers.
//
//   F[b,i,j,k] = 2^(log2e*s) = e^s                (only use of the scores)
//   u_1 = (p1 + F)*r1,          p1 = 2^(-q0[i]), r1 = 1/(1+p1)
//   u_t = (p + F)/(1 + p),      p = u_{t-1} * 2^(-q_{t-1}[i])
//   q_t[k] = q0[k] + mask[k] * sum_i log2(u_s*u_c*u_g)[i,k]
//                               * mask[i]*(i!=j)*(i!=k)
//   out[b,k,j] = 1/(1+2^(-q_3[k]))
//
// Geometry: block (b,j), 1024 thr, 16 waves. Thread = (lane -> k in
// {2*lane, 2*lane+1}, wave wv -> row 16r+wv of tile r, r=0..7).
// fp16 F precision proven r7-r16 (absmax 0.0078 vs threshold 0.02).
// Pass 3 recomputes the chain from F (2 rcp/score).

#define TS 128
#define SS (TS * TS)
#define NREG 3          // tiles 0..2 in registers; 3..7 in LDS

typedef float    f2v __attribute__((ext_vector_type(2)));
typedef _Float16 h2v __attribute__((ext_vector_type(2)));

constexpr float LOG2E = 1.4426950408889634f;

__device__ __forceinline__ float rcpf(float x)   { return __builtin_amdgcn_rcpf(x); }
__device__ __forceinline__ float clampe(float e) { return fminf(fmaxf(e, -126.0f), 60.0f); }
__device__ __forceinline__ float rfl(float x) {   // wave-uniform value -> SGPR
    return __int_as_float(__builtin_amdgcn_readfirstlane(__float_as_int(x)));
}

// ---- single-block mask format probe: f[0]!=0 byte mask, f[1]!=0 f32, else i32
__global__ void mask_probe(const unsigned char* __restrict__ m, int n, int* __restrict__ f) {
    __shared__ int s1, s23;
    if (threadIdx.x == 0) { s1 = 0; s23 = 0; }
    __syncthreads();
    unsigned a1 = 0, a23 = 0;
    const int n16 = n >> 4;
    const uint4* m4 = (const uint4*)m;
    for (int i = threadIdx.x; i < n16; i += 1024) {
        const uint4 v = m4[i];
        const unsigned o = v.x | v.y | v.z | v.w;
        a1  |= o & 0x0000FF00u;
        a23 |= o & 0xFFFF0000u;
    }
    for (int i = (n16 << 4) + threadIdx.x; i < n; i += 1024) {  // tail bytes
        const unsigned char b = m[i];
        const int r = i & 3;
        if (r == 1) a1 |= b;
        if (r >= 2) a23 |= b;
    }
    if (__any(a1 != 0)  && (threadIdx.x & 63) == 0) atomicOr(&s1, 1);
    if (__any(a23 != 0) && (threadIdx.x & 63) == 0) atomicOr(&s23, 1);
    __syncthreads();
    if (threadIdx.x == 0) { f[0] = s1; f[1] = s23; }
}

__global__ __launch_bounds__(1024, 8)
__attribute__((amdgpu_waves_per_eu(8, 8)))
void lbp_fused(const float* __restrict__ s_edge,
               const float* __restrict__ sib,
               const float* __restrict__ cop,
               const float* __restrict__ grd,
               const void* __restrict__ mask,
               const int* __restrict__ flags,
               float* __restrict__ outp)
{
    __shared__ _Float16 FLs[8 - NREG][16][TS];   // 20 KB each: F tiles 3..7
    __shared__ _Float16 FLc[8 - NREG][16][TS];
    __shared__ _Float16 FLg[8 - NREG][16][TS];
    __shared__ float red[16][TS];                // 8 KB: [wave][k]
    __shared__ float q0s[TS], p1s[TS], r1s[TS], g1s[TS], g2s[TS];
    __shared__ unsigned char mrow[TS];

    const int bj = blockIdx.x;
    const int b  = bj >> 7;
    const int j  = bj & (TS - 1);
    const int t  = threadIdx.x;
    const int lane = t & 63;            // k = 2*lane, 2*lane+1
    const int wv = t >> 6;              // wave 0..15; tile r -> row 16r+wv
    const int ka = 2 * lane, kb = 2 * lane + 1;

    // ---- per-column prologue ----
    if (t < TS) {
        const int i = t;
        const int idx = (b * TS + i) * TS + j;
        const float q0 = LOG2E * s_edge[idx];
        q0s[i] = q0;
        const int f1 = flags[0], f23 = flags[1];
        unsigned char mv;
        if (f1)       mv = ((const unsigned char*)mask)[idx] != 0;
        else if (f23) mv = ((const float*)mask)[idx] != 0.0f;
        else          mv = ((const int*)mask)[idx]   != 0;
        mrow[i] = mv;
        const float p1 = exp2f(clampe(-q0));
        p1s[i] = p1;
        r1s[i] = rcpf(1.0f + p1);
    }
    __syncthreads();

    // per-lane element base of (b, row0=wv, j, 2*lane)
    const size_t gbase = (size_t)b * (TS * SS) + (size_t)j * TS + (size_t)wv * SS + ka;

    // ---- pass 1 with register double-buffered direct loads ----
    h2v Fs[NREG], Fc[NREG], Fg[NREG];
    float a0 = 0.0f, a1 = 0.0f;
    f2v vs = *(const f2v*)(sib + gbase);
    f2v vc = *(const f2v*)(cop + gbase);
    f2v vg = *(const f2v*)(grd + gbase);
    #pragma unroll
    for (int r = 0; r < 8; ++r) {
        f2v nvs, nvc, nvg;
        if (r < 7) {
            const size_t g = gbase + (size_t)(16 * (r + 1)) * SS;
            nvs = *(const f2v*)(sib + g);
            nvc = *(const f2v*)(cop + g);
            nvg = *(const f2v*)(grd + g);
        }
        const int i = 16 * r + wv;                 // wave-uniform row
        f2v fs, fc, fg;
        fs[0] = exp2f(LOG2E * vs[0]);  fs[1] = exp2f(LOG2E * vs[1]);
        fc[0] = exp2f(LOG2E * vc[0]);  fc[1] = exp2f(LOG2E * vc[1]);
        fg[0] = exp2f(LOG2E * vg[0]);  fg[1] = exp2f(LOG2E * vg[1]);
        if (r < NREG) {
            Fs[r] = __builtin_convertvector(fs, h2v);
            Fc[r] = __builtin_convertvector(fc, h2v);
            Fg[r] = __builtin_convertvector(fg, h2v);
        } else {
            *(h2v*)&FLs[r - NREG][wv][ka] = __builtin_convertvector(fs, h2v);
            *(h2v*)&FLc[r - NREG][wv][ka] = __builtin_convertvector(fc, h2v);
            *(h2v*)&FLg[r - NREG][wv][ka] = __builtin_convertvector(fg, h2v);
        }
        if ((mrow[i] != 0) && (i != j)) {          // wave-coherent branch
            const float p1 = rfl(p1s[i]), r1 = rfl(r1s[i]);
            const float l0 = __log2f(((p1 + fs[0]) * r1) * ((p1 + fc[0]) * r1)
                                     * ((p1 + fg[0]) * r1));
            const float l1 = __log2f(((p1 + fs[1]) * r1) * ((p1 + fc[1]) * r1)
                                     * ((p1 + fg[1]) * r1));
            if (i != ka) a0 += l0;
            if (i != kb) a1 += l1;
        }
        vs = nvs; vc = nvc; vg = nvg;
    }

    // reduce -> q1 -> g1  (each (wv,k) partial unique: direct store)
    { f2v v; v[0] = a0; v[1] = a1; *(f2v*)&red[wv][ka] = v; }
    __syncthreads();
    if (t < TS) {
        float tot = 0.0f;
        #pragma unroll
        for (int w = 0; w < 16; ++w) tot += red[w][t];
        const float q1 = q0s[t] + (mrow[t] ? tot : 0.0f);
        g1s[t] = exp2f(clampe(-q1));
    }
    __syncthreads();

    // ---- pass 2: u2 via 1 rcp/score, register/LDS F ----
    a0 = 0.0f; a1 = 0.0f;
    #pragma unroll
    for (int r = 0; r < 8; ++r) {
        const int i = 16 * r + wv;
        if ((mrow[i] != 0) && (i != j)) {
            const float p1 = rfl(p1s[i]), r1 = rfl(r1s[i]), g1 = rfl(g1s[i]);
            f2v fs, fc, fg;
            if (r < NREG) {
                fs = __builtin_convertvector(Fs[r], f2v);
                fc = __builtin_convertvector(Fc[r], f2v);
                fg = __builtin_convertvector(Fg[r], f2v);
            } else {
                fs = __builtin_convertvector(*(const h2v*)&FLs[r - NREG][wv][ka], f2v);
                fc = __builtin_convertvector(*(const h2v*)&FLc[r - NREG][wv][ka], f2v);
                fg = __builtin_convertvector(*(const h2v*)&FLg[r - NREG][wv][ka], f2v);
            }
            float l[2];
            #pragma unroll
            for (int c = 0; c < 2; ++c) {
                float p, us, uc, ug;
                us = (p1 + fs[c]) * r1;  p = us * g1;  us = (p + fs[c]) * rcpf(1.0f + p);
                uc = (p1 + fc[c]) * r1;  p = uc * g1;  uc = (p + fc[c]) * rcpf(1.0f + p);
                ug = (p1 + fg[c]) * r1;  p = ug * g1;  ug = (p + fg[c]) * rcpf(1.0f + p);
                l[c] = __log2f(us * uc * ug);
            }
            if (i != ka) a0 += l[0];
            if (i != kb) a1 += l[1];
        }
    }

    // reduce -> q2 -> g2
    { f2v v; v[0] = a0; v[1] = a1; *(f2v*)&red[wv][ka] = v; }
    __syncthreads();
    if (t < TS) {
        float tot = 0.0f;
        #pragma unroll
        for (int w = 0; w < 16; ++w) tot += red[w][t];
        const float q2 = q0s[t] + (mrow[t] ? tot : 0.0f);
        g2s[t] = exp2f(clampe(-q2));
    }
    __syncthreads();

    // ---- pass 3: full chain recompute from F (2 rcp/score) ----
    a0 = 0.0f; a1 = 0.0f;
    #pragma unroll
    for (int r = 0; r < 8; ++r) {
        const int i = 16 * r + wv;
        if ((mrow[i] != 0) && (i != j)) {
            const float p1 = rfl(p1s[i]), r1 = rfl(r1s[i]);
            const float g1 = rfl(g1s[i]), g2 = rfl(g2s[i]);
            f2v fs, fc, fg;
            if (r < NREG) {
                fs = __builtin_convertvector(Fs[r], f2v);
                fc = __builtin_convertvector(Fc[r], f2v);
                fg = __builtin_convertvector(Fg[r], f2v);
            } else {
                fs = __builtin_convertvector(*(const h2v*)&FLs[r - NREG][wv][ka], f2v);
                fc = __builtin_convertvector(*(const h2v*)&FLc[r - NREG][wv][ka], f2v);
                fg = __builtin_convertvector(*(const h2v*)&FLg[r - NREG][wv][ka], f2v);
            }
            float l[2];
            #pragma unroll
            for (int c = 0; c < 2; ++c) {
                float p, us, uc, ug;
                us = (p1 + fs[c]) * r1;  p = us * g1;  us = (p + fs[c]) * rcpf(1.0f + p);
                p = us * g2;  us = (p + fs[c]) * rcpf(1.0f + p);
                uc = (p1 + fc[c]) * r1;  p = uc * g1;  uc = (p + fc[c]) * rcpf(1.0f + p);
                p = uc * g2;  uc = (p + fc[c]) * rcpf(1.0f + p);
                ug = (p1 + fg[c]) * r1;  p = ug * g1;  ug = (p + fg[c]) * rcpf(1.0f + p);
                p = ug * g2;  ug = (p + fg[c]) * rcpf(1.0f + p);
                l[c] = __log2f(us * uc * ug);
            }
            if (i != ka) a0 += l[0];
            if (i != kb) a1 += l[1];
        }
    }

    // reduce -> q3 -> output
    { f2v v; v[0] = a0; v[1] = a1; *(f2v*)&red[wv][ka] = v; }
    __syncthreads();
    if (t < TS) {
        float tot = 0.0f;
        #pragma unroll
        for (int w = 0; w < 16; ++w) tot += red[w][t];
        const float q3 = q0s[t] + (mrow[t] ? tot : 0.0f);
        outp[(b * TS + t) * TS + j] = 1.0f / (1.0f + exp2f(clampe(-q3)));
    }
}

extern "C" void kernel_launch(void* const* d_in, const int* in_sizes, int n_in,
                              void* d_out, int out_size, void* d_ws, size_t ws_size,
                              hipStream_t stream) {
    const float* s_edge = (const float*)d_in[0];
    const float* sib    = (const float*)d_in[1];
    const float* cop    = (const float*)d_in[2];
    const float* grd    = (const float*)d_in[3];
    const void*  mask   = d_in[4];
    float* out = (float*)d_out;

    const int Bn = in_sizes[0] / (TS * TS);   // batch
    const int nMask = in_sizes[4];            // B*S*S elements

    int* flags = (int*)d_ws;

    mask_probe<<<1, 1024, 0, stream>>>((const unsigned char*)mask, nMask, flags);
    lbp_fused<<<Bn * TS, 1024, 0, stream>>>(s_edge, sib, cop, grd, mask, flags, out);
}

// Round 18
// 68.323 us; speedup vs baseline: 1.1925x; 1.0382x over previous
//
#include <hip/hip_runtime.h>

// LBP for semantic dependency parsing — label-difference form, all 3
// iterations fused, u-SPACE chain in PRODUCT FORM, hybrid F storage
// (tiles 0-2 in registers, 3-7 in LDS fp16), 2 blocks/CU, no spill (r17).
//
// r17 counters: VGPR=28 no-spill, occ 79%, FETCH ideal -> VALU-issue-bound
// (49% busy vs 31 us HBM floor). This round cuts issue volume by algebra:
//   l = log2(u_s u_c u_g),  u_x = (p_x+F_x)/(1+p_x)
//     = log2(num) - log2(den),  num = PROD(p_x+F_x), den = PROD(1+p_x)
//   p_x = F_x*(r1*g) + p1*r1*g  -> one fma from wave-uniform constants
// Pass 2: 0 rcp (was 3). Pass 3: 3 rcp (was 6). Exponent clamp +30 keeps
// num <= 2^115 (no overflow); clamp-bind error <= 2e-7.
// F=1 trick: masked/diagonal/i==j elements get F:=1 at staging -> u==1 ->
// zero contribution through ALL passes; deletes per-pass guards.
//
//   F[b,i,j,k] = e^s;  q_t[k] = q0[k] + mask[k]*sum_i l_t[i,k]
//   out[b,k,j] = sigmoid(q_3[k])
//
// Geometry: block (b,j), 1024 thr, 16 waves. Thread = (lane -> k in
// {2*lane, 2*lane+1}, wave wv -> row 16r+wv of tile r, r=0..7).
// fp16 F precision proven r7-r17 (absmax 0.0078 vs threshold 0.02).

#define TS 128
#define SS (TS * TS)
#define NREG 3          // tiles 0..2 in registers; 3..7 in LDS

typedef float    f2v __attribute__((ext_vector_type(2)));
typedef _Float16 h2v __attribute__((ext_vector_type(2)));

constexpr float LOG2E = 1.4426950408889634f;

__device__ __forceinline__ float rcpf(float x)   { return __builtin_amdgcn_rcpf(x); }
__device__ __forceinline__ float clampe(float e) { return fminf(fmaxf(e, -126.0f), 30.0f); }
__device__ __forceinline__ float rfl(float x) {   // wave-uniform value -> SGPR
    return __int_as_float(__builtin_amdgcn_readfirstlane(__float_as_int(x)));
}

// ---- single-block mask format probe: f[0]!=0 byte mask, f[1]!=0 f32, else i32
__global__ void mask_probe(const unsigned char* __restrict__ m, int n, int* __restrict__ f) {
    __shared__ int s1, s23;
    if (threadIdx.x == 0) { s1 = 0; s23 = 0; }
    __syncthreads();
    unsigned a1 = 0, a23 = 0;
    const int n16 = n >> 4;
    const uint4* m4 = (const uint4*)m;
    for (int i = threadIdx.x; i < n16; i += 1024) {
        const uint4 v = m4[i];
        const unsigned o = v.x | v.y | v.z | v.w;
        a1  |= o & 0x0000FF00u;
        a23 |= o & 0xFFFF0000u;
    }
    for (int i = (n16 << 4) + threadIdx.x; i < n; i += 1024) {  // tail bytes
        const unsigned char b = m[i];
        const int r = i & 3;
        if (r == 1) a1 |= b;
        if (r >= 2) a23 |= b;
    }
    if (__any(a1 != 0)  && (threadIdx.x & 63) == 0) atomicOr(&s1, 1);
    if (__any(a23 != 0) && (threadIdx.x & 63) == 0) atomicOr(&s23, 1);
    __syncthreads();
    if (threadIdx.x == 0) { f[0] = s1; f[1] = s23; }
}

__global__ __launch_bounds__(1024, 8)
__attribute__((amdgpu_waves_per_eu(8, 8)))
void lbp_fused(const float* __restrict__ s_edge,
               const float* __restrict__ sib,
               const float* __restrict__ cop,
               const float* __restrict__ grd,
               const void* __restrict__ mask,
               const int* __restrict__ flags,
               float* __restrict__ outp)
{
    __shared__ _Float16 FLs[8 - NREG][16][TS];   // 20 KB each: F tiles 3..7
    __shared__ _Float16 FLc[8 - NREG][16][TS];
    __shared__ _Float16 FLg[8 - NREG][16][TS];
    __shared__ float red[16][TS];                // 8 KB: [wave][k]
    __shared__ float q0s[TS], p1s[TS], r1s[TS], lp3s[TS], g1s[TS], g2s[TS];
    __shared__ unsigned char mrow[TS];

    const int bj = blockIdx.x;
    const int b  = bj >> 7;
    const int j  = bj & (TS - 1);
    const int t  = threadIdx.x;
    const int lane = t & 63;            // k = 2*lane, 2*lane+1
    const int wv = t >> 6;              // wave 0..15; tile r -> row 16r+wv
    const int ka = 2 * lane, kb = 2 * lane + 1;

    // ---- per-column prologue ----
    if (t < TS) {
        const int i = t;
        const int idx = (b * TS + i) * TS + j;
        const float q0 = LOG2E * s_edge[idx];
        q0s[i] = q0;
        const int f1 = flags[0], f23 = flags[1];
        unsigned char mv;
        if (f1)       mv = ((const unsigned char*)mask)[idx] != 0;
        else if (f23) mv = ((const float*)mask)[idx] != 0.0f;
        else          mv = ((const int*)mask)[idx]   != 0;
        mrow[i] = mv;
        const float p1 = exp2f(clampe(-q0));
        p1s[i]  = p1;
        r1s[i]  = rcpf(1.0f + p1);
        lp3s[i] = 3.0f * __log2f(1.0f + p1);
    }
    __syncthreads();

    // per-lane element base of (b, row0=wv, j, 2*lane)
    const size_t gbase = (size_t)b * (TS * SS) + (size_t)j * TS + (size_t)wv * SS + ka;

    // ---- pass 1 with register double-buffered direct loads ----
    // F staged with F:=1 for dead elements (masked row, i==j, i==k):
    // u==1 through the whole chain -> zero contribution, no guards later.
    h2v Fs[NREG], Fc[NREG], Fg[NREG];
    float a0 = 0.0f, a1 = 0.0f;
    f2v vs = *(const f2v*)(sib + gbase);
    f2v vc = *(const f2v*)(cop + gbase);
    f2v vg = *(const f2v*)(grd + gbase);
    #pragma unroll
    for (int r = 0; r < 8; ++r) {
        f2v nvs, nvc, nvg;
        if (r < 7) {
            const size_t g = gbase + (size_t)(16 * (r + 1)) * SS;
            nvs = *(const f2v*)(sib + g);
            nvc = *(const f2v*)(cop + g);
            nvg = *(const f2v*)(grd + g);
        }
        const int i = 16 * r + wv;                 // wave-uniform row
        const bool live = (mrow[i] != 0) && (i != j);
        f2v fs, fc, fg;
        #pragma unroll
        for (int c = 0; c < 2; ++c) {
            const bool on = live && (i != ka + c);
            fs[c] = on ? exp2f(LOG2E * vs[c]) : 1.0f;
            fc[c] = on ? exp2f(LOG2E * vc[c]) : 1.0f;
            fg[c] = on ? exp2f(LOG2E * vg[c]) : 1.0f;
        }
        if (r < NREG) {
            Fs[r] = __builtin_convertvector(fs, h2v);
            Fc[r] = __builtin_convertvector(fc, h2v);
            Fg[r] = __builtin_convertvector(fg, h2v);
        } else {
            *(h2v*)&FLs[r - NREG][wv][ka] = __builtin_convertvector(fs, h2v);
            *(h2v*)&FLc[r - NREG][wv][ka] = __builtin_convertvector(fc, h2v);
            *(h2v*)&FLg[r - NREG][wv][ka] = __builtin_convertvector(fg, h2v);
        }
        // l1 = log2((p1+Fs)(p1+Fc)(p1+Fg)) - 3*log2(1+p1); dead rows -> ~0
        const float p1 = rfl(p1s[i]), lp3 = rfl(lp3s[i]);
        a0 += __log2f((p1 + fs[0]) * (p1 + fc[0]) * (p1 + fg[0])) - lp3;
        a1 += __log2f((p1 + fs[1]) * (p1 + fc[1]) * (p1 + fg[1])) - lp3;
        vs = nvs; vc = nvc; vg = nvg;
    }

    // reduce -> q1 -> g1  (each (wv,k) partial unique: direct store)
    { f2v v; v[0] = a0; v[1] = a1; *(f2v*)&red[wv][ka] = v; }
    __syncthreads();
    if (t < TS) {
        float tot = 0.0f;
        #pragma unroll
        for (int w = 0; w < 16; ++w) tot += red[w][t];
        const float q1 = q0s[t] + (mrow[t] ? tot : 0.0f);
        g1s[t] = exp2f(clampe(-q1));
    }
    __syncthreads();

    // ---- pass 2: product form, ZERO rcp ----
    // p_x = F_x*m1 + c1;  ax = p_x+F_x = fma(F_x, 1+m1, c1);
    // bx = 1+p_x = fma(F_x, m1, 1+c1);  l2 = log2(PROD ax) - log2(PROD bx)
    a0 = 0.0f; a1 = 0.0f;
    #pragma unroll
    for (int r = 0; r < 8; ++r) {
        const int i = 16 * r + wv;
        const float m1  = rfl(r1s[i]) * rfl(g1s[i]);
        const float c1  = rfl(p1s[i]) * m1;
        const float m1p = 1.0f + m1;
        const float c1p = 1.0f + c1;
        f2v fs, fc, fg;
        if (r < NREG) {
            fs = __builtin_convertvector(Fs[r], f2v);
            fc = __builtin_convertvector(Fc[r], f2v);
            fg = __builtin_convertvector(Fg[r], f2v);
        } else {
            fs = __builtin_convertvector(*(const h2v*)&FLs[r - NREG][wv][ka], f2v);
            fc = __builtin_convertvector(*(const h2v*)&FLc[r - NREG][wv][ka], f2v);
            fg = __builtin_convertvector(*(const h2v*)&FLg[r - NREG][wv][ka], f2v);
        }
        float l[2];
        #pragma unroll
        for (int c = 0; c < 2; ++c) {
            const float as = fmaf(fs[c], m1p, c1), bs = fmaf(fs[c], m1, c1p);
            const float ac = fmaf(fc[c], m1p, c1), bc = fmaf(fc[c], m1, c1p);
            const float ag = fmaf(fg[c], m1p, c1), bg = fmaf(fg[c], m1, c1p);
            l[c] = __log2f(as * ac * ag) - __log2f(bs * bc * bg);
        }
        a0 += l[0];
        a1 += l[1];
    }

    // reduce -> q2 -> g2
    { f2v v; v[0] = a0; v[1] = a1; *(f2v*)&red[wv][ka] = v; }
    __syncthreads();
    if (t < TS) {
        float tot = 0.0f;
        #pragma unroll
        for (int w = 0; w < 16; ++w) tot += red[w][t];
        const float q2 = q0s[t] + (mrow[t] ? tot : 0.0f);
        g2s[t] = exp2f(clampe(-q2));
    }
    __syncthreads();

    // ---- pass 3: u2 = ax*rcp(bx) (3 rcp), then product form again ----
    a0 = 0.0f; a1 = 0.0f;
    #pragma unroll
    for (int r = 0; r < 8; ++r) {
        const int i = 16 * r + wv;
        const float m1  = rfl(r1s[i]) * rfl(g1s[i]);
        const float c1  = rfl(p1s[i]) * m1;
        const float m1p = 1.0f + m1;
        const float c1p = 1.0f + c1;
        const float g2  = rfl(g2s[i]);
        f2v fs, fc, fg;
        if (r < NREG) {
            fs = __builtin_convertvector(Fs[r], f2v);
            fc = __builtin_convertvector(Fc[r], f2v);
            fg = __builtin_convertvector(Fg[r], f2v);
        } else {
            fs = __builtin_convertvector(*(const h2v*)&FLs[r - NREG][wv][ka], f2v);
            fc = __builtin_convertvector(*(const h2v*)&FLc[r - NREG][wv][ka], f2v);
            fg = __builtin_convertvector(*(const h2v*)&FLg[r - NREG][wv][ka], f2v);
        }
        float l[2];
        #pragma unroll
        for (int c = 0; c < 2; ++c) {
            const float us = fmaf(fs[c], m1p, c1) * rcpf(fmaf(fs[c], m1, c1p));
            const float uc = fmaf(fc[c], m1p, c1) * rcpf(fmaf(fc[c], m1, c1p));
            const float ug = fmaf(fg[c], m1p, c1) * rcpf(fmaf(fg[c], m1, c1p));
            const float ps = us * g2, pc = uc * g2, pg = ug * g2;
            l[c] = __log2f((ps + fs[c]) * (pc + fc[c]) * (pg + fg[c]))
                 - __log2f((1.0f + ps) * (1.0f + pc) * (1.0f + pg));
        }
        a0 += l[0];
        a1 += l[1];
    }

    // reduce -> q3 -> output
    { f2v v; v[0] = a0; v[1] = a1; *(f2v*)&red[wv][ka] = v; }
    __syncthreads();
    if (t < TS) {
        float tot = 0.0f;
        #pragma unroll
        for (int w = 0; w < 16; ++w) tot += red[w][t];
        const float q3 = q0s[t] + (mrow[t] ? tot : 0.0f);
        outp[(b * TS + t) * TS + j] = 1.0f / (1.0f + exp2f(clampe(-q3)));
    }
}

extern "C" void kernel_launch(void* const* d_in, const int* in_sizes, int n_in,
                              void* d_out, int out_size, void* d_ws, size_t ws_size,
                              hipStream_t stream) {
    const float* s_edge = (const float*)d_in[0];
    const float* sib    = (const float*)d_in[1];
    const float* cop    = (const float*)d_in[2];
    const float* grd    = (const float*)d_in[3];
    const void*  mask   = d_in[4];
    float* out = (float*)d_out;

    const int Bn = in_sizes[0] / (TS * TS);   // batch
    const int nMask = in_sizes[4];            // B*S*S elements

    int* flags = (int*)d_ws;

    mask_probe<<<1, 1024, 0, stream>>>((const unsigned char*)mask, nMask, flags);
    lbp_fused<<<Bn * TS, 1024, 0, stream>>>(s_edge, sib, cop, grd, mask, flags, out);
}

// Round 19
// 63.410 us; speedup vs baseline: 1.2849x; 1.0775x over previous
//
#include <hip/hip_runtime.h>

// LBP for semantic dependency parsing — label-difference form, all 3
// iterations fused, u-SPACE chain in PRODUCT FORM, hybrid F storage
// (tiles 0-2 in registers, 3-7 in LDS fp16), 2 blocks/CU.
//
// r18 post-mortem: product-form algebra cut VALUBusy 49->37% (dur 70.9->68.3)
// but full unrolling + wide expression trees re-spilled the 32-VGPR tier
// (WRITE 4->37 MB scratch). This round: PRESSURE-SHAPED loops — each 8-tile
// loop splits into an unrolled head (tiles 0-2, register F: compile-time
// indices required) and a '#pragma unroll 1' tail (tiles 3-7, LDS F:
// runtime addressing is fine). Bounds in-flight loads to one tile and
// narrows temp lifetimes to one iteration; TLP at 82% occupancy hides the
// per-iteration latency. Target: true demand <= 32 regs, zero scratch.
//
//   F[b,i,j,k] = e^s  (F:=1 for masked/diagonal elements -> u==1 -> zero
//   contribution through ALL passes; no per-pass guards)
//   l = log2(PROD_x (p_x+F_x)) - log2(PROD_x (1+p_x)),
//   p_x = F_x*m + c from wave-uniform constants (one fma each)
//   q_t[k] = q0[k] + mask[k]*sum_i l_t[i,k];  out[b,k,j] = sigmoid(q_3[k])
// Exponent clamp +30: num <= 2^115, no overflow; clamp-bind error <= 2e-7.
//
// Geometry: block (b,j), 1024 thr, 16 waves. Thread = (lane -> k in
// {2*lane, 2*lane+1}, wave wv -> row 16r+wv of tile r, r=0..7).
// fp16 F precision proven r7-r18 (absmax 0.0078 vs threshold 0.02).

#define TS 128
#define SS (TS * TS)
#define NREG 3          // tiles 0..2 in registers; 3..7 in LDS

typedef float    f2v __attribute__((ext_vector_type(2)));
typedef _Float16 h2v __attribute__((ext_vector_type(2)));

constexpr float LOG2E = 1.4426950408889634f;

__device__ __forceinline__ float rcpf(float x)   { return __builtin_amdgcn_rcpf(x); }
__device__ __forceinline__ float clampe(float e) { return fminf(fmaxf(e, -126.0f), 30.0f); }
__device__ __forceinline__ float rfl(float x) {   // wave-uniform value -> SGPR
    return __int_as_float(__builtin_amdgcn_readfirstlane(__float_as_int(x)));
}

// ---- single-block mask format probe: f[0]!=0 byte mask, f[1]!=0 f32, else i32
__global__ void mask_probe(const unsigned char* __restrict__ m, int n, int* __restrict__ f) {
    __shared__ int s1, s23;
    if (threadIdx.x == 0) { s1 = 0; s23 = 0; }
    __syncthreads();
    unsigned a1 = 0, a23 = 0;
    const int n16 = n >> 4;
    const uint4* m4 = (const uint4*)m;
    for (int i = threadIdx.x; i < n16; i += 1024) {
        const uint4 v = m4[i];
        const unsigned o = v.x | v.y | v.z | v.w;
        a1  |= o & 0x0000FF00u;
        a23 |= o & 0xFFFF0000u;
    }
    for (int i = (n16 << 4) + threadIdx.x; i < n; i += 1024) {  // tail bytes
        const unsigned char b = m[i];
        const int r = i & 3;
        if (r == 1) a1 |= b;
        if (r >= 2) a23 |= b;
    }
    if (__any(a1 != 0)  && (threadIdx.x & 63) == 0) atomicOr(&s1, 1);
    if (__any(a23 != 0) && (threadIdx.x & 63) == 0) atomicOr(&s23, 1);
    __syncthreads();
    if (threadIdx.x == 0) { f[0] = s1; f[1] = s23; }
}

__global__ __launch_bounds__(1024, 8)
__attribute__((amdgpu_waves_per_eu(8, 8)))
void lbp_fused(const float* __restrict__ s_edge,
               const float* __restrict__ sib,
               const float* __restrict__ cop,
               const float* __restrict__ grd,
               const void* __restrict__ mask,
               const int* __restrict__ flags,
               float* __restrict__ outp)
{
    __shared__ _Float16 FLs[8 - NREG][16][TS];   // 20 KB each: F tiles 3..7
    __shared__ _Float16 FLc[8 - NREG][16][TS];
    __shared__ _Float16 FLg[8 - NREG][16][TS];
    __shared__ float red[16][TS];                // 8 KB: [wave][k]
    __shared__ float q0s[TS], p1s[TS], r1s[TS], lp3s[TS], g1s[TS], g2s[TS];
    __shared__ unsigned char mrow[TS];

    const int bj = blockIdx.x;
    const int b  = bj >> 7;
    const int j  = bj & (TS - 1);
    const int t  = threadIdx.x;
    const int lane = t & 63;            // k = 2*lane, 2*lane+1
    const int wv = t >> 6;              // wave 0..15; tile r -> row 16r+wv
    const int ka = 2 * lane, kb = 2 * lane + 1;

    // ---- per-column prologue ----
    if (t < TS) {
        const int i = t;
        const int idx = (b * TS + i) * TS + j;
        const float q0 = LOG2E * s_edge[idx];
        q0s[i] = q0;
        const int f1 = flags[0], f23 = flags[1];
        unsigned char mv;
        if (f1)       mv = ((const unsigned char*)mask)[idx] != 0;
        else if (f23) mv = ((const float*)mask)[idx] != 0.0f;
        else          mv = ((const int*)mask)[idx]   != 0;
        mrow[i] = mv;
        const float p1 = exp2f(clampe(-q0));
        p1s[i]  = p1;
        r1s[i]  = rcpf(1.0f + p1);
        lp3s[i] = 3.0f * __log2f(1.0f + p1);
    }
    __syncthreads();

    // per-lane element base of (b, row0=wv, j, 2*lane)
    const size_t gbase = (size_t)b * (TS * SS) + (size_t)j * TS + (size_t)wv * SS + ka;

    h2v Fs[NREG], Fc[NREG], Fg[NREG];
    float a0 = 0.0f, a1 = 0.0f;

    // ---- pass 1, head: tiles 0..2 -> register F (compile-time indices) ----
    #pragma unroll
    for (int r = 0; r < NREG; ++r) {
        const size_t g = gbase + (size_t)(16 * r) * SS;
        const f2v vs = *(const f2v*)(sib + g);
        const f2v vc = *(const f2v*)(cop + g);
        const f2v vg = *(const f2v*)(grd + g);
        const int i = 16 * r + wv;                 // wave-uniform row
        const bool live = (mrow[i] != 0) && (i != j);
        f2v fs, fc, fg;
        #pragma unroll
        for (int c = 0; c < 2; ++c) {
            const bool on = live && (i != ka + c);
            fs[c] = on ? exp2f(LOG2E * vs[c]) : 1.0f;
            fc[c] = on ? exp2f(LOG2E * vc[c]) : 1.0f;
            fg[c] = on ? exp2f(LOG2E * vg[c]) : 1.0f;
        }
        Fs[r] = __builtin_convertvector(fs, h2v);
        Fc[r] = __builtin_convertvector(fc, h2v);
        Fg[r] = __builtin_convertvector(fg, h2v);
        const float p1 = rfl(p1s[i]), lp3 = rfl(lp3s[i]);
        a0 += __log2f((p1 + fs[0]) * (p1 + fc[0]) * (p1 + fg[0])) - lp3;
        a1 += __log2f((p1 + fs[1]) * (p1 + fc[1]) * (p1 + fg[1])) - lp3;
    }
    // ---- pass 1, tail: tiles 3..7 -> LDS F (runtime addressing, unroll 1) ----
    #pragma unroll 1
    for (int r = NREG; r < 8; ++r) {
        const size_t g = gbase + (size_t)(16 * r) * SS;
        const f2v vs = *(const f2v*)(sib + g);
        const f2v vc = *(const f2v*)(cop + g);
        const f2v vg = *(const f2v*)(grd + g);
        const int i = 16 * r + wv;
        const bool live = (mrow[i] != 0) && (i != j);
        f2v fs, fc, fg;
        #pragma unroll
        for (int c = 0; c < 2; ++c) {
            const bool on = live && (i != ka + c);
            fs[c] = on ? exp2f(LOG2E * vs[c]) : 1.0f;
            fc[c] = on ? exp2f(LOG2E * vc[c]) : 1.0f;
            fg[c] = on ? exp2f(LOG2E * vg[c]) : 1.0f;
        }
        *(h2v*)&FLs[r - NREG][wv][ka] = __builtin_convertvector(fs, h2v);
        *(h2v*)&FLc[r - NREG][wv][ka] = __builtin_convertvector(fc, h2v);
        *(h2v*)&FLg[r - NREG][wv][ka] = __builtin_convertvector(fg, h2v);
        const float p1 = rfl(p1s[i]), lp3 = rfl(lp3s[i]);
        a0 += __log2f((p1 + fs[0]) * (p1 + fc[0]) * (p1 + fg[0])) - lp3;
        a1 += __log2f((p1 + fs[1]) * (p1 + fc[1]) * (p1 + fg[1])) - lp3;
    }

    // reduce -> q1 -> g1  (each (wv,k) partial unique: direct store)
    { f2v v; v[0] = a0; v[1] = a1; *(f2v*)&red[wv][ka] = v; }
    __syncthreads();
    if (t < TS) {
        float tot = 0.0f;
        #pragma unroll
        for (int w = 0; w < 16; ++w) tot += red[w][t];
        const float q1 = q0s[t] + (mrow[t] ? tot : 0.0f);
        g1s[t] = exp2f(clampe(-q1));
    }
    __syncthreads();

    // ---- pass 2: product form, ZERO rcp ----
    a0 = 0.0f; a1 = 0.0f;
    #pragma unroll
    for (int r = 0; r < NREG; ++r) {
        const int i = 16 * r + wv;
        const float m1  = rfl(r1s[i]) * rfl(g1s[i]);
        const float c1  = rfl(p1s[i]) * m1;
        const float m1p = 1.0f + m1;
        const float c1p = 1.0f + c1;
        const f2v fs = __builtin_convertvector(Fs[r], f2v);
        const f2v fc = __builtin_convertvector(Fc[r], f2v);
        const f2v fg = __builtin_convertvector(Fg[r], f2v);
        #pragma unroll
        for (int c = 0; c < 2; ++c) {
            const float as = fmaf(fs[c], m1p, c1), bs = fmaf(fs[c], m1, c1p);
            const float ac = fmaf(fc[c], m1p, c1), bc = fmaf(fc[c], m1, c1p);
            const float ag = fmaf(fg[c], m1p, c1), bg = fmaf(fg[c], m1, c1p);
            const float l = __log2f(as * ac * ag) - __log2f(bs * bc * bg);
            if (c == 0) a0 += l; else a1 += l;
        }
    }
    #pragma unroll 1
    for (int r = NREG; r < 8; ++r) {
        const int i = 16 * r + wv;
        const float m1  = rfl(r1s[i]) * rfl(g1s[i]);
        const float c1  = rfl(p1s[i]) * m1;
        const float m1p = 1.0f + m1;
        const float c1p = 1.0f + c1;
        const f2v fs = __builtin_convertvector(*(const h2v*)&FLs[r - NREG][wv][ka], f2v);
        const f2v fc = __builtin_convertvector(*(const h2v*)&FLc[r - NREG][wv][ka], f2v);
        const f2v fg = __builtin_convertvector(*(const h2v*)&FLg[r - NREG][wv][ka], f2v);
        #pragma unroll
        for (int c = 0; c < 2; ++c) {
            const float as = fmaf(fs[c], m1p, c1), bs = fmaf(fs[c], m1, c1p);
            const float ac = fmaf(fc[c], m1p, c1), bc = fmaf(fc[c], m1, c1p);
            const float ag = fmaf(fg[c], m1p, c1), bg = fmaf(fg[c], m1, c1p);
            const float l = __log2f(as * ac * ag) - __log2f(bs * bc * bg);
            if (c == 0) a0 += l; else a1 += l;
        }
    }

    // reduce -> q2 -> g2
    { f2v v; v[0] = a0; v[1] = a1; *(f2v*)&red[wv][ka] = v; }
    __syncthreads();
    if (t < TS) {
        float tot = 0.0f;
        #pragma unroll
        for (int w = 0; w < 16; ++w) tot += red[w][t];
        const float q2 = q0s[t] + (mrow[t] ? tot : 0.0f);
        g2s[t] = exp2f(clampe(-q2));
    }
    __syncthreads();

    // ---- pass 3: u2 = ax*rcp(bx) (3 rcp), then product form again ----
    a0 = 0.0f; a1 = 0.0f;
    #pragma unroll
    for (int r = 0; r < NREG; ++r) {
        const int i = 16 * r + wv;
        const float m1  = rfl(r1s[i]) * rfl(g1s[i]);
        const float c1  = rfl(p1s[i]) * m1;
        const float m1p = 1.0f + m1;
        const float c1p = 1.0f + c1;
        const float g2  = rfl(g2s[i]);
        const f2v fs = __builtin_convertvector(Fs[r], f2v);
        const f2v fc = __builtin_convertvector(Fc[r], f2v);
        const f2v fg = __builtin_convertvector(Fg[r], f2v);
        #pragma unroll
        for (int c = 0; c < 2; ++c) {
            const float us = fmaf(fs[c], m1p, c1) * rcpf(fmaf(fs[c], m1, c1p));
            const float uc = fmaf(fc[c], m1p, c1) * rcpf(fmaf(fc[c], m1, c1p));
            const float ug = fmaf(fg[c], m1p, c1) * rcpf(fmaf(fg[c], m1, c1p));
            const float ps = us * g2, pc = uc * g2, pg = ug * g2;
            const float l = __log2f((ps + fs[c]) * (pc + fc[c]) * (pg + fg[c]))
                          - __log2f((1.0f + ps) * (1.0f + pc) * (1.0f + pg));
            if (c == 0) a0 += l; else a1 += l;
        }
    }
    #pragma unroll 1
    for (int r = NREG; r < 8; ++r) {
        const int i = 16 * r + wv;
        const float m1  = rfl(r1s[i]) * rfl(g1s[i]);
        const float c1  = rfl(p1s[i]) * m1;
        const float m1p = 1.0f + m1;
        const float c1p = 1.0f + c1;
        const float g2  = rfl(g2s[i]);
        const f2v fs = __builtin_convertvector(*(const h2v*)&FLs[r - NREG][wv][ka], f2v);
        const f2v fc = __builtin_convertvector(*(const h2v*)&FLc[r - NREG][wv][ka], f2v);
        const f2v fg = __builtin_convertvector(*(const h2v*)&FLg[r - NREG][wv][ka], f2v);
        #pragma unroll
        for (int c = 0; c < 2; ++c) {
            const float us = fmaf(fs[c], m1p, c1) * rcpf(fmaf(fs[c], m1, c1p));
            const float uc = fmaf(fc[c], m1p, c1) * rcpf(fmaf(fc[c], m1, c1p));
            const float ug = fmaf(fg[c], m1p, c1) * rcpf(fmaf(fg[c], m1, c1p));
            const float ps = us * g2, pc = uc * g2, pg = ug * g2;
            const float l = __log2f((ps + fs[c]) * (pc + fc[c]) * (pg + fg[c]))
                          - __log2f((1.0f + ps) * (1.0f + pc) * (1.0f + pg));
            if (c == 0) a0 += l; else a1 += l;
        }
    }

    // reduce -> q3 -> output
    { f2v v; v[0] = a0; v[1] = a1; *(f2v*)&red[wv][ka] = v; }
    __syncthreads();
    if (t < TS) {
        float tot = 0.0f;
        #pragma unroll
        for (int w = 0; w < 16; ++w) tot += red[w][t];
        const float q3 = q0s[t] + (mrow[t] ? tot : 0.0f);
        outp[(b * TS + t) * TS + j] = 1.0f / (1.0f + exp2f(clampe(-q3)));
    }
}

extern "C" void kernel_launch(void* const* d_in, const int* in_sizes, int n_in,
                              void* d_out, int out_size, void* d_ws, size_t ws_size,
                              hipStream_t stream) {
    const float* s_edge = (const float*)d_in[0];
    const float* sib    = (const float*)d_in[1];
    const float* cop    = (const float*)d_in[2];
    const float* grd    = (const float*)d_in[3];
    const void*  mask   = d_in[4];
    float* out = (float*)d_out;

    const int Bn = in_sizes[0] / (TS * TS);   // batch
    const int nMask = in_sizes[4];            // B*S*S elements

    int* flags = (int*)d_ws;

    mask_probe<<<1, 1024, 0, stream>>>((const unsigned char*)mask, nMask, flags);
    lbp_fused<<<Bn * TS, 1024, 0, stream>>>(s_edge, sib, cop, grd, mask, flags, out);
}